// Round 8
// baseline (416.109 us; speedup 1.0000x reference)
//
#include <hip/hip_runtime.h>
#include <hip/hip_bf16.h>
#include <cstdint>

// Problem shape (Transducer joint network):
//   enc (4,160,640) fp32, dec (4,80,640) fp32, W1 (1280,640), b1 (640),
//   W2 (640,1024), b2 (1024).  out = (4,160,80,1024) fp32 = 52.4M floats.
#define D_    640
#define V_    1024
#define M_    51200

typedef __bf16 bf16x8 __attribute__((ext_vector_type(8)));
typedef float floatx4 __attribute__((ext_vector_type(4)));

__device__ __forceinline__ float fast_tanh(float x) {
    float e = __builtin_amdgcn_exp2f(x * 2.8853900817779268f); // 2*log2(e)
    return 1.0f - 2.0f * __builtin_amdgcn_rcpf(e + 1.0f);
}

// ---------------------------------------------------------------------------
// Kernel 1: fp32 projections -> d_ws. 64x64 tiles, 4x4/thread.
// b1 FOLDED into encp (k-only bias): hidden = tanh((e+b1) + d).
// ---------------------------------------------------------------------------
__global__ __launch_bounds__(256) void proj_kernel(
    const float* __restrict__ enc, const float* __restrict__ dec,
    const float* __restrict__ W1, const float* __restrict__ b1,
    float* __restrict__ encp, float* __restrict__ decp) {
    __shared__ float As[64][36];
    __shared__ float Ws[32][68];

    const int rt = blockIdx.y;     // 0..14 (10 enc row-tiles, 5 dec row-tiles)
    const int ct = blockIdx.x;     // 0..9
    const bool is_enc = (rt < 10);
    const float* Asrc; const float* Wsrc; float* Cdst;
    if (is_enc) { Asrc = enc + (size_t)rt * 64 * D_;        Wsrc = W1;           Cdst = encp + (size_t)rt * 64 * D_; }
    else        { Asrc = dec + (size_t)(rt - 10) * 64 * D_; Wsrc = W1 + D_ * D_; Cdst = decp + (size_t)(rt - 10) * 64 * D_; }

    const int tid = threadIdx.x;
    const int ar = tid >> 2,  ac = (tid & 3) * 8;
    const int wr2 = tid >> 3, wc2 = (tid & 7) * 8;
    const int tr = tid >> 4,  tc = tid & 15;

    float acc[4][4] = {};
    for (int k0 = 0; k0 < D_; k0 += 32) {
        __syncthreads();
        *(floatx4*)&As[ar][ac]       = *(const floatx4*)&Asrc[(size_t)ar * D_ + k0 + ac];
        *(floatx4*)&As[ar][ac + 4]   = *(const floatx4*)&Asrc[(size_t)ar * D_ + k0 + ac + 4];
        *(floatx4*)&Ws[wr2][wc2]     = *(const floatx4*)&Wsrc[(size_t)(k0 + wr2) * D_ + ct * 64 + wc2];
        *(floatx4*)&Ws[wr2][wc2 + 4] = *(const floatx4*)&Wsrc[(size_t)(k0 + wr2) * D_ + ct * 64 + wc2 + 4];
        __syncthreads();
#pragma unroll
        for (int kk = 0; kk < 32; kk++) {
            floatx4 w = *(const floatx4*)&Ws[kk][tc * 4];
            float a0 = As[tr * 4 + 0][kk], a1 = As[tr * 4 + 1][kk];
            float a2 = As[tr * 4 + 2][kk], a3 = As[tr * 4 + 3][kk];
#pragma unroll
            for (int j = 0; j < 4; j++) {
                acc[0][j] += a0 * w[j]; acc[1][j] += a1 * w[j];
                acc[2][j] += a2 * w[j]; acc[3][j] += a3 * w[j];
            }
        }
    }
    floatx4 bv = {0.f, 0.f, 0.f, 0.f};
    if (is_enc) bv = *(const floatx4*)&b1[ct * 64 + tc * 4];
#pragma unroll
    for (int i = 0; i < 4; i++) {
        floatx4 v = { acc[i][0] + bv[0], acc[i][1] + bv[1],
                      acc[i][2] + bv[2], acc[i][3] + bv[3] };
        *(floatx4*)&Cdst[(size_t)(tr * 4 + i) * D_ + ct * 64 + tc * 4] = v;
    }
}

// ---------------------------------------------------------------------------
// Kernel 2: W2 (640x1024 fp32 KxN) -> W2t (1024x640 bf16 NxK) in d_ws.
// ---------------------------------------------------------------------------
__global__ __launch_bounds__(256) void w2t_kernel(
    const float* __restrict__ W2, __bf16* __restrict__ W2t) {
    __shared__ __bf16 tile[32][33];
    const int vt = blockIdx.x;           // 0..31
    const int kt = blockIdx.y;           // 0..19
    const int tx = threadIdx.x & 31, ty = threadIdx.x >> 5;
#pragma unroll
    for (int i = 0; i < 4; i++)
        tile[ty + i * 8][tx] = (__bf16)W2[(size_t)(kt * 32 + ty + i * 8) * V_ + vt * 32 + tx];
    __syncthreads();
#pragma unroll
    for (int i = 0; i < 4; i++)
        W2t[(size_t)(vt * 32 + ty + i * 8) * D_ + kt * 32 + tx] = tile[tx][ty + i * 8];
}

// ---------------------------------------------------------------------------
// Kernel 3 (fused): C = tanh(encp'[bt] + decp[drw]) @ W2t^T + b2.
// r5 geometry/structure (best: 137us) + two structural cuts from r5's PMC
// decomposition (LDS 47% / VMEM 43% / VALU 37% / MFMA 23% — all summing):
//
// 1) B DIRECT L2->REG (no LDS for B): B bytes have zero intra-block reuse
//    (each byte feeds one wave once; reuse is register-level across af's),
//    so g2l staging was pure overhead. Deletes 64KB/block-tile of LDS
//    traffic; LDS now A-only 2x8KB. The per-tile barrier then orders ONLY
//    LDS ops -> raw s_barrier + lgkmcnt(0) (NOT __syncthreads: no vmcnt
//    drain), so next-tile B loads stay in flight across barriers (T4 for
//    free). sched_barrier(0) after, per guide rule #18.
//    B frags double-buffered in NAMED regs bA/bB via unroll-2 (no copies —
//    r6 lesson).
// 2) SWAPPED-OPERAND MFMA: mfma(bfr, af) instead of (af, bfr) — fragments
//    have identical lane layouts so swap is free; acc reg index becomes the
//    N-dim => thread's 4 acc values are 4 CONSECUTIVE C columns =>
//    global_store_dwordx4 + float4 bias (16 stores/thread vs 64 + addr VALU).
//
// Same conflict-free involution slot16 ^= (row&7) on the A LDS paths
// (r5-verified: 0 conflicts).
// ---------------------------------------------------------------------------
__global__ __launch_bounds__(256, 2) void joint_kernel(
    const float* __restrict__ encp, const float* __restrict__ decp,
    const __bf16* __restrict__ W2t, const float* __restrict__ b2,
    float* __restrict__ C) {
    __shared__ __align__(128) char lds[16384];      // A only: 2 x 8KB

    const int bid = blockIdx.x;
    const int swz = (bid & 7) * 400 + (bid >> 3);   // 3200 = 8 XCD x 400
    const int mt = swz >> 2, nt = swz & 3;          // 800 M-tiles x 4 N-tiles
    const int m0 = mt * 64, n0 = nt * 256;

    const int tid = threadIdx.x;                    // 0..255
    const int w = tid >> 6, l = tid & 63;           // 4 waves; wave = N-col w
    const int lr = l & 15, lk = l >> 4;

    char* ldsp = (char*)lds;

    // ---- B direct-load base: this lane's W2t row (= C col) and k-slot.
    const char* Wb = (const char*)W2t
        + (size_t)(n0 + w * 64 + lr) * 1280 + (unsigned)(lk * 16);

    // ---- A produce: thread owns row pr (0..63), k-quarter kq (16 elems).
    const int pr = tid >> 2;
    const int kq = tid & 3;
    const int R  = m0 + pr;
    const int bt = R / 80;
    const int uu = R - bt * 80;
    const int drw = (bt / 160) * 80 + uu;
    const float* ep = encp + (size_t)bt * D_ + kq * 16;   // b1 already folded in
    const float* dp = decp + (size_t)drw * D_ + kq * 16;
    const unsigned prb = (unsigned)(pr * 128);
    const unsigned pw0 = prb + (unsigned)((((kq * 2)     ^ (pr & 7)) * 16));
    const unsigned pw1 = prb + (unsigned)((((kq * 2 + 1) ^ (pr & 7)) * 16));

    // accT[j][i]: j = N sub-tile, i = M sub-tile (swapped-operand layout)
    floatx4 accT[4][4] = {};

// B frags for tile T -> DST[0..3] = k-step 0, DST[4..7] = k-step 1.
#define LOAD_BFR(DST, T) do { \
    const char* _b = Wb + (size_t)(T) * 128; \
    _Pragma("unroll") for (int j = 0; j < 4; ++j) { \
        DST[j]     = *(const bf16x8*)(_b + (size_t)(j * 16) * 1280); \
        DST[j + 4] = *(const bf16x8*)(_b + (size_t)(j * 16) * 1280 + 64); \
    } } while (0)

#define PRODUCE_A(BUF, T) do { \
    const float* _e = ep + (T) * 64; const float* _d = dp + (T) * 64; \
    floatx4 ev[4], dv[4]; \
    _Pragma("unroll") for (int q = 0; q < 4; ++q) { \
      ev[q] = *(const floatx4*)(_e + q * 4); \
      dv[q] = *(const floatx4*)(_d + q * 4); \
    } \
    bf16x8 h0, h1; \
    _Pragma("unroll") for (int q = 0; q < 4; ++q) \
      _Pragma("unroll") for (int i2 = 0; i2 < 4; ++i2) { \
        float t_ = fast_tanh(ev[q][i2] + dv[q][i2]); \
        if (q < 2) h0[q * 4 + i2] = (__bf16)t_; else h1[(q - 2) * 4 + i2] = (__bf16)t_; \
      } \
    *(bf16x8*)(ldsp + (BUF) * 8192 + pw0) = h0; \
    *(bf16x8*)(ldsp + (BUF) * 8192 + pw1) = h1; \
  } while (0)

// A frags from LDS buffer BUF + MFMA against B regs (swapped operands).
#define FRAGS_MFMA(BUF, BFR) do { \
    _Pragma("unroll") for (int s = 0; s < 2; ++s) { \
        const unsigned sx = (unsigned)((((s * 4 + lk) ^ (lr & 7)) * 16)); \
        bf16x8 af[4]; \
        _Pragma("unroll") for (int i = 0; i < 4; ++i) \
            af[i] = *(const bf16x8*)(ldsp + (BUF) * 8192 + (i * 16 + lr) * 128 + sx); \
        _Pragma("unroll") for (int j = 0; j < 4; ++j) \
            _Pragma("unroll") for (int i = 0; i < 4; ++i) \
                accT[j][i] = __builtin_amdgcn_mfma_f32_16x16x32_bf16(BFR[s * 4 + j], af[i], accT[j][i], 0, 0, 0); \
    } } while (0)

#define ABAR do { \
    asm volatile("s_waitcnt lgkmcnt(0)" ::: "memory"); \
    __builtin_amdgcn_s_barrier(); \
    __builtin_amdgcn_sched_barrier(0); \
  } while (0)

    bf16x8 bA[8], bB[8];

    // ---- prologue: B(0) -> bA, produce A(0) -> buf0 ----
    LOAD_BFR(bA, 0);
    PRODUCE_A(0, 0);
    ABAR;

#pragma unroll 1
    for (int t = 0; t < 10; t += 2) {
        // even tile t: reads buf0 + bA; prefetch odd tile's B and A
        LOAD_BFR(bB, t + 1);               // stays in flight across barrier
        FRAGS_MFMA(0, bA);
        PRODUCE_A(1, t + 1);
        ABAR;
        // odd tile t+1: reads buf1 + bB; prefetch next even tile
        if (t < 8) LOAD_BFR(bA, t + 2);
        FRAGS_MFMA(1, bB);
        if (t < 8) PRODUCE_A(0, t + 2);
        ABAR;
    }

    // ---- epilogue (swapped layout): lane&15 = M-row, (lane>>4)*4+reg = N-col
    // -> 4 regs are 4 consecutive C columns: dwordx4 stores + float4 bias.
#pragma unroll
    for (int j = 0; j < 4; ++j) {
        const int col0 = n0 + w * 64 + j * 16 + lk * 4;
        const floatx4 bv = *(const floatx4*)&b2[col0];
#pragma unroll
        for (int i = 0; i < 4; ++i) {
            const int row = m0 + i * 16 + lr;
            floatx4 v = { accT[j][i][0] + bv[0], accT[j][i][1] + bv[1],
                          accT[j][i][2] + bv[2], accT[j][i][3] + bv[3] };
            *(floatx4*)&C[(size_t)row * V_ + col0] = v;
        }
    }
#undef LOAD_BFR
#undef PRODUCE_A
#undef FRAGS_MFMA
#undef ABAR
}

// ---------------------------------------------------------------------------
extern "C" void kernel_launch(void* const* d_in, const int* in_sizes, int n_in,
                              void* d_out, int out_size, void* d_ws, size_t ws_size,
                              hipStream_t stream) {
    const float* enc = (const float*)d_in[0];
    const float* dec = (const float*)d_in[1];
    const float* W1  = (const float*)d_in[2];
    const float* b1  = (const float*)d_in[3];
    const float* W2  = (const float*)d_in[4];
    const float* b2  = (const float*)d_in[5];
    float* out = (float*)d_out;

    // Workspace (d_ws):
    char* ws = (char*)d_ws;
    float*  encp = (float*)ws;                         // 640*640*4  = 1,638,400 (b1 folded)
    float*  decp = (float*)(ws + 1638400);             // 320*640*4  =   819,200
    __bf16* W2t  = (__bf16*)(ws + 1638400 + 819200);   // 1024*640*2 = 1,310,720

    proj_kernel<<<dim3(10, 15), 256, 0, stream>>>(enc, dec, W1, b1, encp, decp);
    w2t_kernel<<<dim3(32, 20), 256, 0, stream>>>(W2, W2t);
    joint_kernel<<<3200, 256, 0, stream>>>(encp, decp, W2t, b2, out);
}

// Round 9
// 355.928 us; speedup vs baseline: 1.1691x; 1.1691x over previous
//
#include <hip/hip_runtime.h>
#include <hip/hip_bf16.h>
#include <cstdint>

// Problem shape (Transducer joint network):
//   enc (4,160,640) fp32, dec (4,80,640) fp32, W1 (1280,640), b1 (640),
//   W2 (640,1024), b2 (1024).  out = (4,160,80,1024) fp32 = 52.4M floats.
#define D_    640
#define V_    1024
#define M_    51200

typedef __bf16 bf16x8 __attribute__((ext_vector_type(8)));
typedef float floatx4 __attribute__((ext_vector_type(4)));

__device__ __forceinline__ void g2l16(const void* g, void* l) {
    __builtin_amdgcn_global_load_lds((const __attribute__((address_space(1))) void*)g,
                                     (__attribute__((address_space(3))) void*)l,
                                     16, 0, 0);
}

__device__ __forceinline__ float fast_tanh(float x) {
    float e = __builtin_amdgcn_exp2f(x * 2.8853900817779268f); // 2*log2(e)
    return 1.0f - 2.0f * __builtin_amdgcn_rcpf(e + 1.0f);
}

// ---------------------------------------------------------------------------
// Kernel 1: fp32 projections -> d_ws. 64x64 tiles, 4x4/thread.
// b1 FOLDED into encp (k-only bias): hidden = tanh((e+b1) + d).
// ---------------------------------------------------------------------------
__global__ __launch_bounds__(256) void proj_kernel(
    const float* __restrict__ enc, const float* __restrict__ dec,
    const float* __restrict__ W1, const float* __restrict__ b1,
    float* __restrict__ encp, float* __restrict__ decp) {
    __shared__ float As[64][36];
    __shared__ float Ws[32][68];

    const int rt = blockIdx.y;     // 0..14 (10 enc row-tiles, 5 dec row-tiles)
    const int ct = blockIdx.x;     // 0..9
    const bool is_enc = (rt < 10);
    const float* Asrc; const float* Wsrc; float* Cdst;
    if (is_enc) { Asrc = enc + (size_t)rt * 64 * D_;        Wsrc = W1;           Cdst = encp + (size_t)rt * 64 * D_; }
    else        { Asrc = dec + (size_t)(rt - 10) * 64 * D_; Wsrc = W1 + D_ * D_; Cdst = decp + (size_t)(rt - 10) * 64 * D_; }

    const int tid = threadIdx.x;
    const int ar = tid >> 2,  ac = (tid & 3) * 8;
    const int wr2 = tid >> 3, wc2 = (tid & 7) * 8;
    const int tr = tid >> 4,  tc = tid & 15;

    float acc[4][4] = {};
    for (int k0 = 0; k0 < D_; k0 += 32) {
        __syncthreads();
        *(floatx4*)&As[ar][ac]       = *(const floatx4*)&Asrc[(size_t)ar * D_ + k0 + ac];
        *(floatx4*)&As[ar][ac + 4]   = *(const floatx4*)&Asrc[(size_t)ar * D_ + k0 + ac + 4];
        *(floatx4*)&Ws[wr2][wc2]     = *(const floatx4*)&Wsrc[(size_t)(k0 + wr2) * D_ + ct * 64 + wc2];
        *(floatx4*)&Ws[wr2][wc2 + 4] = *(const floatx4*)&Wsrc[(size_t)(k0 + wr2) * D_ + ct * 64 + wc2 + 4];
        __syncthreads();
#pragma unroll
        for (int kk = 0; kk < 32; kk++) {
            floatx4 w = *(const floatx4*)&Ws[kk][tc * 4];
            float a0 = As[tr * 4 + 0][kk], a1 = As[tr * 4 + 1][kk];
            float a2 = As[tr * 4 + 2][kk], a3 = As[tr * 4 + 3][kk];
#pragma unroll
            for (int j = 0; j < 4; j++) {
                acc[0][j] += a0 * w[j]; acc[1][j] += a1 * w[j];
                acc[2][j] += a2 * w[j]; acc[3][j] += a3 * w[j];
            }
        }
    }
    floatx4 bv = {0.f, 0.f, 0.f, 0.f};
    if (is_enc) bv = *(const floatx4*)&b1[ct * 64 + tc * 4];
#pragma unroll
    for (int i = 0; i < 4; i++) {
        floatx4 v = { acc[i][0] + bv[0], acc[i][1] + bv[1],
                      acc[i][2] + bv[2], acc[i][3] + bv[3] };
        *(floatx4*)&Cdst[(size_t)(tr * 4 + i) * D_ + ct * 64 + tc * 4] = v;
    }
}

// ---------------------------------------------------------------------------
// Kernel 2: W2 (640x1024 fp32 KxN) -> W2t (1024x640 bf16 NxK) in d_ws.
// ---------------------------------------------------------------------------
__global__ __launch_bounds__(256) void w2t_kernel(
    const float* __restrict__ W2, __bf16* __restrict__ W2t) {
    __shared__ __bf16 tile[32][33];
    const int vt = blockIdx.x;           // 0..31
    const int kt = blockIdx.y;           // 0..19
    const int tx = threadIdx.x & 31, ty = threadIdx.x >> 5;
#pragma unroll
    for (int i = 0; i < 4; i++)
        tile[ty + i * 8][tx] = (__bf16)W2[(size_t)(kt * 32 + ty + i * 8) * V_ + vt * 32 + tx];
    __syncthreads();
#pragma unroll
    for (int i = 0; i < 4; i++)
        W2t[(size_t)(vt * 32 + ty + i * 8) * D_ + kt * 32 + tx] = tile[tx][ty + i * 8];
}

// ---------------------------------------------------------------------------
// Kernel 3: hidden[m][h] = tanh(encp'[bt][h] + decp[b*80+u][h]) -> bf16.
// (b1 pre-folded into encp.) tanh computed ONCE per element — r5..r8's fused
// produce re-computed it 4x (once per N-tile) and re-loaded fp32 e+d 4x:
// that duplication was ~37% VALUBusy + half the L2 pole. 15us here buys both back.
// ---------------------------------------------------------------------------
__global__ __launch_bounds__(256) void hidden_kernel(
    const float* __restrict__ encp, const float* __restrict__ decp,
    __bf16* __restrict__ H) {
    const unsigned g = blockIdx.x * 256u + threadIdx.x;  // 0..4,095,999
    const unsigned row = g / 80u;   // m index 0..51199
    const unsigned hg  = g % 80u;   // h-group (8 elems)
    const unsigned u   = row % 80u;
    const unsigned bt  = row / 80u;
    const unsigned b   = bt / 160u;

    const float* ep = encp + (size_t)bt * D_ + hg * 8;
    const float* dp = decp + (size_t)(b * 80u + u) * D_ + hg * 8;

    floatx4 e0 = *(const floatx4*)ep, e1 = *(const floatx4*)(ep + 4);
    floatx4 d0 = *(const floatx4*)dp, d1 = *(const floatx4*)(dp + 4);

    bf16x8 hv;
#pragma unroll
    for (int i = 0; i < 4; i++) hv[i]     = (__bf16)fast_tanh(e0[i] + d0[i]);
#pragma unroll
    for (int i = 0; i < 4; i++) hv[i + 4] = (__bf16)fast_tanh(e1[i] + d1[i]);

    *(bf16x8*)(H + (size_t)g * 8) = hv;
}

// ---------------------------------------------------------------------------
// Kernel 4: C[51200x1024] = H @ W2t^T + b2.
// BM=128, BN=256, BK=32, 256 thr = 4 waves (1M x 4N), wave out = 128x64
// (acc[8][4]: frag reuse 8x4 -> 12 ds_read_b128 per 32 MFMAs per wave-tile).
// LDS 48KB (A 2x8KB @0, B 2x16KB @16384) -> 2 blocks/CU; ZERO ds_writes
// (both operands g2l-staged, fully coalesced — r8 proved reg-direct B is a
// 16-segment gather and loses).
// BK=32 -> 64B LDS rows; conflict-free needs the 2-BIT involution
//   slot16 ^= (row>>1)&3
// (4 slots x row-parity -> a frag read puts exactly 8 accesses on every
// bank; r4's 1-row-period swizzle failed because 64B rows only span 16
// banks). (row>>1)&3 is invariant under +64-row batch offsets and under
// i*16/j*16/w*64 row offsets -> folds to a per-lane constant on both the
// staging source and the read side.
// Swapped-operand MFMA (bfr first) -> acc reg index = N => verified (r8)
// dwordx4 C stores with float4 bias.
// ---------------------------------------------------------------------------
__global__ __launch_bounds__(256, 2) void gemm_kernel(
    const __bf16* __restrict__ H, const __bf16* __restrict__ W2t,
    const float* __restrict__ b2, float* __restrict__ C) {
    __shared__ __align__(128) char lds[49152];   // A: 2x8KB @0, B: 2x16KB @16384

    const int bid = blockIdx.x;
    const int swz = (bid & 7) * 200 + (bid >> 3);   // 1600 = 8 XCD x 200
    const int mt = swz >> 2, nt = swz & 3;          // 400 M-tiles x 4 N-tiles
    const int m0 = mt * 128, n0 = nt * 256;

    const int tid = threadIdx.x;                    // 0..255
    const int w = tid >> 6, l = tid & 63;           // 4 waves; wave = N-col w
    const int lr = l & 15, lk = l >> 4;

    char* ldsp = (char*)lds;

    // ---- staging: thread covers row srow(+64b), phys slot sphy; source col
    // pre-swizzled by the involution so linear LDS dest lands swizzled.
    const int srow = tid >> 2;                      // 0..63
    const int sphy = tid & 3;
    const unsigned scol = (unsigned)((sphy ^ ((srow >> 1) & 3)) * 16);
    const char* Ag = (const char*)H   + (size_t)(m0 + srow) * 1280 + scol;
    const char* Bg = (const char*)W2t + (size_t)(n0 + srow) * 1280 + scol;
    const unsigned sdst = (unsigned)tid * 16u;

    // ---- frag reads: phys slot = lk ^ ((row>>1)&3) = lk ^ ((lr>>1)&3).
    const unsigned px16 = (unsigned)((lk ^ ((lr >> 1) & 3)) * 16);

    // accT[j][i]: j = N sub-tile (4), i = M sub-tile (8) — swapped-operand.
    floatx4 accT[4][8] = {};

#define STAGE_A(BUF, T) do { \
    g2l16(Ag + (T) * 64,          ldsp + (BUF) * 8192 + sdst); \
    g2l16(Ag + 81920 + (T) * 64,  ldsp + (BUF) * 8192 + sdst + 4096); \
  } while (0)
#define STAGE_B(BUF, T) do { \
    g2l16(Bg + (T) * 64,           ldsp + 16384 + (BUF) * 16384 + sdst); \
    g2l16(Bg +  81920 + (T) * 64,  ldsp + 16384 + (BUF) * 16384 + sdst + 4096); \
    g2l16(Bg + 163840 + (T) * 64,  ldsp + 16384 + (BUF) * 16384 + sdst + 8192); \
    g2l16(Bg + 245760 + (T) * 64,  ldsp + 16384 + (BUF) * 16384 + sdst + 12288); \
  } while (0)

#define FRAGS_MFMA(BUF) do { \
    bf16x8 af[8], bfr[4]; \
    _Pragma("unroll") for (int i = 0; i < 8; ++i) \
        af[i] = *(const bf16x8*)(ldsp + (BUF) * 8192 + (i * 16 + lr) * 64 + px16); \
    _Pragma("unroll") for (int j = 0; j < 4; ++j) \
        bfr[j] = *(const bf16x8*)(ldsp + 16384 + (BUF) * 16384 + (w * 64 + j * 16 + lr) * 64 + px16); \
    _Pragma("unroll") for (int j = 0; j < 4; ++j) \
        _Pragma("unroll") for (int i = 0; i < 8; ++i) \
            accT[j][i] = __builtin_amdgcn_mfma_f32_16x16x32_bf16(bfr[j], af[i], accT[j][i], 0, 0, 0); \
  } while (0)

    // ---- prologue ----
    STAGE_A(0, 0); STAGE_B(0, 0);
    __syncthreads();

#pragma unroll 1
    for (int t = 0; t < 20; ++t) {                 // 20 K-tiles of 32
        const int buf = t & 1, nb = buf ^ 1;
        if (t < 19) { STAGE_A(nb, t + 1); STAGE_B(nb, t + 1); }
        FRAGS_MFMA(buf);
        __syncthreads();                           // drains stage + readers
    }

    // ---- epilogue (swapped layout, r8-verified): lane&15 = M-row,
    // (lane>>4)*4 + reg = N-col -> 4 regs = 4 consecutive C columns.
#pragma unroll
    for (int j = 0; j < 4; ++j) {
        const int col0 = n0 + w * 64 + j * 16 + lk * 4;
        const floatx4 bv = *(const floatx4*)&b2[col0];
#pragma unroll
        for (int i = 0; i < 8; ++i) {
            const int row = m0 + i * 16 + lr;
            floatx4 v = { accT[j][i][0] + bv[0], accT[j][i][1] + bv[1],
                          accT[j][i][2] + bv[2], accT[j][i][3] + bv[3] };
            *(floatx4*)&C[(size_t)row * V_ + col0] = v;
        }
    }
#undef STAGE_A
#undef STAGE_B
#undef FRAGS_MFMA
}

// ---------------------------------------------------------------------------
extern "C" void kernel_launch(void* const* d_in, const int* in_sizes, int n_in,
                              void* d_out, int out_size, void* d_ws, size_t ws_size,
                              hipStream_t stream) {
    const float* enc = (const float*)d_in[0];
    const float* dec = (const float*)d_in[1];
    const float* W1  = (const float*)d_in[2];
    const float* b1  = (const float*)d_in[3];
    const float* W2  = (const float*)d_in[4];
    const float* b2  = (const float*)d_in[5];
    float* out = (float*)d_out;

    // Workspace (d_ws), ~69.3 MB:
    char* ws = (char*)d_ws;
    float*  encp = (float*)ws;                                   // 640*640*4   = 1,638,400 (b1 folded)
    float*  decp = (float*)(ws + 1638400);                       // 320*640*4   =   819,200
    __bf16* W2t  = (__bf16*)(ws + 1638400 + 819200);             // 1024*640*2  = 1,310,720
    __bf16* Hbuf = (__bf16*)(ws + 1638400 + 819200 + 1310720);   // 51200*640*2 = 65,536,000

    proj_kernel<<<dim3(10, 15), 256, 0, stream>>>(enc, dec, W1, b1, encp, decp);
    w2t_kernel<<<dim3(32, 20), 256, 0, stream>>>(W2, W2t);
    hidden_kernel<<<16000, 256, 0, stream>>>(encp, decp, Hbuf);
    gemm_kernel<<<1600, 256, 0, stream>>>(Hbuf, W2t, b2, out);
}

// Round 10
// 352.434 us; speedup vs baseline: 1.1807x; 1.0099x over previous
//
#include <hip/hip_runtime.h>
#include <hip/hip_bf16.h>
#include <cstdint>

// Problem shape (Transducer joint network):
//   enc (4,160,640) fp32, dec (4,80,640) fp32, W1 (1280,640), b1 (640),
//   W2 (640,1024), b2 (1024).  out = (4,160,80,1024) fp32 = 52.4M floats.
#define D_    640
#define V_    1024
#define M_    51200

typedef __bf16 bf16x8 __attribute__((ext_vector_type(8)));
typedef float floatx4 __attribute__((ext_vector_type(4)));

__device__ __forceinline__ void g2l16(const void* g, void* l) {
    __builtin_amdgcn_global_load_lds((const __attribute__((address_space(1))) void*)g,
                                     (__attribute__((address_space(3))) void*)l,
                                     16, 0, 0);
}

__device__ __forceinline__ float fast_tanh(float x) {
    float e = __builtin_amdgcn_exp2f(x * 2.8853900817779268f); // 2*log2(e)
    return 1.0f - 2.0f * __builtin_amdgcn_rcpf(e + 1.0f);
}

// ---------------------------------------------------------------------------
// Kernel 1: fp32 projections -> d_ws. 64x64 tiles, 4x4/thread.
// b1 FOLDED into encp (k-only bias): hidden = tanh((e+b1) + d).
// ---------------------------------------------------------------------------
__global__ __launch_bounds__(256) void proj_kernel(
    const float* __restrict__ enc, const float* __restrict__ dec,
    const float* __restrict__ W1, const float* __restrict__ b1,
    float* __restrict__ encp, float* __restrict__ decp) {
    __shared__ float As[64][36];
    __shared__ float Ws[32][68];

    const int rt = blockIdx.y;     // 0..14 (10 enc row-tiles, 5 dec row-tiles)
    const int ct = blockIdx.x;     // 0..9
    const bool is_enc = (rt < 10);
    const float* Asrc; const float* Wsrc; float* Cdst;
    if (is_enc) { Asrc = enc + (size_t)rt * 64 * D_;        Wsrc = W1;           Cdst = encp + (size_t)rt * 64 * D_; }
    else        { Asrc = dec + (size_t)(rt - 10) * 64 * D_; Wsrc = W1 + D_ * D_; Cdst = decp + (size_t)(rt - 10) * 64 * D_; }

    const int tid = threadIdx.x;
    const int ar = tid >> 2,  ac = (tid & 3) * 8;
    const int wr2 = tid >> 3, wc2 = (tid & 7) * 8;
    const int tr = tid >> 4,  tc = tid & 15;

    float acc[4][4] = {};
    for (int k0 = 0; k0 < D_; k0 += 32) {
        __syncthreads();
        *(floatx4*)&As[ar][ac]       = *(const floatx4*)&Asrc[(size_t)ar * D_ + k0 + ac];
        *(floatx4*)&As[ar][ac + 4]   = *(const floatx4*)&Asrc[(size_t)ar * D_ + k0 + ac + 4];
        *(floatx4*)&Ws[wr2][wc2]     = *(const floatx4*)&Wsrc[(size_t)(k0 + wr2) * D_ + ct * 64 + wc2];
        *(floatx4*)&Ws[wr2][wc2 + 4] = *(const floatx4*)&Wsrc[(size_t)(k0 + wr2) * D_ + ct * 64 + wc2 + 4];
        __syncthreads();
#pragma unroll
        for (int kk = 0; kk < 32; kk++) {
            floatx4 w = *(const floatx4*)&Ws[kk][tc * 4];
            float a0 = As[tr * 4 + 0][kk], a1 = As[tr * 4 + 1][kk];
            float a2 = As[tr * 4 + 2][kk], a3 = As[tr * 4 + 3][kk];
#pragma unroll
            for (int j = 0; j < 4; j++) {
                acc[0][j] += a0 * w[j]; acc[1][j] += a1 * w[j];
                acc[2][j] += a2 * w[j]; acc[3][j] += a3 * w[j];
            }
        }
    }
    floatx4 bv = {0.f, 0.f, 0.f, 0.f};
    if (is_enc) bv = *(const floatx4*)&b1[ct * 64 + tc * 4];
#pragma unroll
    for (int i = 0; i < 4; i++) {
        floatx4 v = { acc[i][0] + bv[0], acc[i][1] + bv[1],
                      acc[i][2] + bv[2], acc[i][3] + bv[3] };
        *(floatx4*)&Cdst[(size_t)(tr * 4 + i) * D_ + ct * 64 + tc * 4] = v;
    }
}

// ---------------------------------------------------------------------------
// Kernel 2: W2 (640x1024 fp32 KxN) -> W2t (1024x640 bf16 NxK) in d_ws.
// ---------------------------------------------------------------------------
__global__ __launch_bounds__(256) void w2t_kernel(
    const float* __restrict__ W2, __bf16* __restrict__ W2t) {
    __shared__ __bf16 tile[32][33];
    const int vt = blockIdx.x;           // 0..31
    const int kt = blockIdx.y;           // 0..19
    const int tx = threadIdx.x & 31, ty = threadIdx.x >> 5;
#pragma unroll
    for (int i = 0; i < 4; i++)
        tile[ty + i * 8][tx] = (__bf16)W2[(size_t)(kt * 32 + ty + i * 8) * V_ + vt * 32 + tx];
    __syncthreads();
#pragma unroll
    for (int i = 0; i < 4; i++)
        W2t[(size_t)(vt * 32 + ty + i * 8) * D_ + kt * 32 + tx] = tile[tx][ty + i * 8];
}

// ---------------------------------------------------------------------------
// Kernel 3: hidden[m][h] = tanh(encp'[bt][h] + decp[b*80+u][h]) -> bf16.
// tanh once per element (fused variants re-computed it 4x — r8 lesson).
// ---------------------------------------------------------------------------
__global__ __launch_bounds__(256) void hidden_kernel(
    const float* __restrict__ encp, const float* __restrict__ decp,
    __bf16* __restrict__ H) {
    const unsigned g = blockIdx.x * 256u + threadIdx.x;  // 0..4,095,999
    const unsigned row = g / 80u;
    const unsigned hg  = g % 80u;
    const unsigned u   = row % 80u;
    const unsigned bt  = row / 80u;
    const unsigned b   = bt / 160u;

    const float* ep = encp + (size_t)bt * D_ + hg * 8;
    const float* dp = decp + (size_t)(b * 80u + u) * D_ + hg * 8;

    floatx4 e0 = *(const floatx4*)ep, e1 = *(const floatx4*)(ep + 4);
    floatx4 d0 = *(const floatx4*)dp, d1 = *(const floatx4*)(dp + 4);

    bf16x8 hv;
#pragma unroll
    for (int i = 0; i < 4; i++) hv[i]     = (__bf16)fast_tanh(e0[i] + d0[i]);
#pragma unroll
    for (int i = 0; i < 4; i++) hv[i + 4] = (__bf16)fast_tanh(e1[i] + d1[i]);

    *(bf16x8*)(H + (size_t)g * 8) = hv;
}

// ---------------------------------------------------------------------------
// Kernel 4: C[51200x1024] = H @ W2t^T + b2.
// r1's verified 256x256 8-phase schedule with ONE change: GRAY-CODE quadrant
// order (0,0)->(1,0)->(1,1)->(0,1). Each phase reads only the operand that
// CHANGED (af or bg held in regs across phases): 12/8/4/8 = 32 frag-reads
// per K-tile vs r1's 48 — the LDS pole (the dominant per-phase cost) drops
// ~33%. Re-derived slice staging is perfectly uniform (ONE half-slice = 2
// g2l16 per phase) and the waits converge to the m201 spec exactly:
// vmcnt(6) at P3 and P7 only (N = 2 loads x 3 half-tiles in flight).
// Window audit (steady state):
//   P0: stage t(2it+1).A0  [buf1.A0 free since prev P7; read this P4]
//   P1: t(2it+2).B0 | P2: .A1 | P3: .B1 | P4: .A0   [into buf0]
//   P5: t(2it+3).B0 | P6: .A1 | P7: .B1             [into buf1]
//   wait@P3 covers P4-reads (counts: 7 slices in flight, need thru 4th ->
//   vmcnt(6)); wait@P7 covers next-P0-reads (same count). it=4: P3 -> vmcnt(0).
// Accumulation order per acc quadrant unchanged vs r1 (bit-identical output).
// ---------------------------------------------------------------------------
#define VM6  asm volatile("s_waitcnt vmcnt(6)" ::: "memory")
#define VM0  asm volatile("s_waitcnt vmcnt(0)" ::: "memory")
#define BAR  __builtin_amdgcn_s_barrier()
#define SCB  __builtin_amdgcn_sched_barrier(0)

#define STG_A(BUF, S, TL) do { \
    g2l16(Hb + (unsigned)((S)*163840 + (TL)*128) + agl,         ldsp + (BUF)*32768 + (S)*16384 + stl); \
    g2l16(Hb + (unsigned)((S)*163840 + (TL)*128 + 10240) + agl, ldsp + (BUF)*32768 + (S)*16384 + stl + 1024); \
  } while (0)
#define STG_B(BUF, S, TL) do { \
    g2l16(Wb + (unsigned)((S)*163840 + (TL)*128) + agl,         ldsp + 65536 + (BUF)*32768 + (S)*16384 + stl); \
    g2l16(Wb + (unsigned)((S)*163840 + (TL)*128 + 10240) + agl, ldsp + 65536 + (BUF)*32768 + (S)*16384 + stl + 1024); \
  } while (0)

#define RD_A(ABUF, QM) do { \
    _Pragma("unroll") for (int ii = 0; ii < 4; ++ii) { \
      af0[ii] = *(const bf16x8*)(ldsp + (ABUF)*32768 + (QM)*16384 + ii*2048 + aRowB + sx0); \
      af1[ii] = *(const bf16x8*)(ldsp + (ABUF)*32768 + (QM)*16384 + ii*2048 + aRowB + sx1); \
    } } while (0)
#define RD_B(BBUF, QN) do { \
    _Pragma("unroll") for (int jj = 0; jj < 2; ++jj) { \
      bg0[jj] = *(const bf16x8*)(ldsp + 65536 + (BBUF)*32768 + (QN)*16384 + jj*2048 + bRowB + sx0); \
      bg1[jj] = *(const bf16x8*)(ldsp + 65536 + (BBUF)*32768 + (QN)*16384 + jj*2048 + bRowB + sx1); \
    } } while (0)
#define MM(QM, QN) do { \
    __builtin_amdgcn_s_setprio(1); \
    _Pragma("unroll") for (int ii = 0; ii < 4; ++ii) \
      _Pragma("unroll") for (int jj = 0; jj < 2; ++jj) { \
        acc[(QM)*4+ii][(QN)*2+jj] = __builtin_amdgcn_mfma_f32_16x16x32_bf16(af0[ii], bg0[jj], acc[(QM)*4+ii][(QN)*2+jj], 0, 0, 0); \
        acc[(QM)*4+ii][(QN)*2+jj] = __builtin_amdgcn_mfma_f32_16x16x32_bf16(af1[ii], bg1[jj], acc[(QM)*4+ii][(QN)*2+jj], 0, 0, 0); \
      } \
    __builtin_amdgcn_s_setprio(0); \
  } while (0)

__global__ __launch_bounds__(512, 2) void gemm_kernel(
    const __bf16* __restrict__ H, const __bf16* __restrict__ W2t,
    const float* __restrict__ b2, float* __restrict__ C) {
    __shared__ __align__(128) char lds[131072];   // A: [0,64K), B: [64K,128K)

    // XCD swizzle: 800 blocks, 8 XCDs, 100 contiguous per XCD (r1-verified).
    const int bid = blockIdx.x;
    const int swz = (bid & 7) * 100 + (bid >> 3);
    const int mt = swz >> 2, nt = swz & 3;        // 200 M-tiles x 4 N-tiles
    const int m0 = mt * 256, n0 = nt * 256;

    const int tid = threadIdx.x;
    const int w = tid >> 6, l = tid & 63;
    const int wr = w >> 2, wc = w & 3;            // 2 x 4 wave grid
    const int lrow = l & 15, lk = l >> 4, l7 = l & 7, lhi = l >> 3;

    // staging: pre-swizzled global source, linear LDS dest (r1-verified).
    const unsigned swzb = (unsigned)(((l & 7) ^ lhi) * 16);
    const unsigned agl  = (unsigned)((w * 16 + lhi) * 1280) + swzb;
    const unsigned stl  = (unsigned)(w * 2048 + l * 16);

    const char* Hb = (const char*)H   + (size_t)m0 * 1280;
    const char* Wb = (const char*)W2t + (size_t)n0 * 1280;
    char* ldsp = (char*)lds;

    // ds_read constants (same XOR involution as staging).
    const unsigned aRowB = (unsigned)((wr * 64 + lrow) * 128);
    const unsigned bRowB = (unsigned)(wc * 4096 + lrow * 128);
    const unsigned sx0 = (unsigned)(((0 + lk) ^ l7) * 16);
    const unsigned sx1 = (unsigned)(((4 + lk) ^ l7) * 16);

    floatx4 acc[8][4] = {};

    // ---- prologue: t0 {A0,B0,A1,B1} + t1 {B0,A1,B1} = 7 slices; wait 6 ----
    STG_A(0, 0, 0); STG_B(0, 0, 0); STG_A(0, 1, 0); STG_B(0, 1, 0);
    STG_B(1, 0, 1); STG_A(1, 1, 1); STG_B(1, 1, 1);
    VM6; BAR; SCB;

#pragma unroll 1
    for (int it = 0; it < 5; ++it) {              // 10 K-tiles, 2 per iter
        const int t1 = 2 * it + 1, t2 = 2 * it + 2, t3 = 2 * it + 3;
        const bool g = (it < 4);
        bf16x8 af0[4], af1[4], bg0[2], bg1[2];

        // ---- group 0: buf0 (tile 2it), Gray order ----
        RD_A(0, 0); RD_B(0, 0);
        STG_A(1, 0, t1);
        BAR; SCB; MM(0, 0); BAR; SCB;

        RD_A(0, 1);
        if (g) STG_B(0, 0, t2);
        BAR; SCB; MM(1, 0); BAR; SCB;

        RD_B(0, 1);
        if (g) STG_A(0, 1, t2);
        BAR; SCB; MM(1, 1); BAR; SCB;

        RD_A(0, 0);
        if (g) STG_B(0, 1, t2);
        if (it == 4) { VM0; } else { VM6; }
        BAR; SCB; MM(0, 1); BAR; SCB;

        // ---- group 1: buf1 (tile 2it+1), Gray order ----
        RD_A(1, 0); RD_B(1, 0);
        if (g) STG_A(0, 0, t2);
        BAR; SCB; MM(0, 0); BAR; SCB;

        RD_A(1, 1);
        if (g) STG_B(1, 0, t3);
        BAR; SCB; MM(1, 0); BAR; SCB;

        RD_B(1, 1);
        if (g) STG_A(1, 1, t3);
        BAR; SCB; MM(1, 1); BAR; SCB;

        RD_A(1, 0);
        if (g) STG_B(1, 1, t3);
        if (g) { VM6; }
        BAR; SCB; MM(0, 1); BAR; SCB;
    }

    // ---- epilogue (r1-verified): col = lane&15 within 16-col frag ----
#pragma unroll
    for (int j = 0; j < 4; ++j) {
        const int col = n0 + (j >> 1) * 128 + wc * 32 + (j & 1) * 16 + lrow;
        const float bj = b2[col];
#pragma unroll
        for (int i = 0; i < 8; ++i) {
            const int row = m0 + (i >> 2) * 128 + wr * 64 + (i & 3) * 16 + lk * 4;
            float* Cp = C + (size_t)row * V_ + col;
#pragma unroll
            for (int rg = 0; rg < 4; ++rg)
                Cp[(size_t)rg * V_] = acc[i][j][rg] + bj;
        }
    }
}

// ---------------------------------------------------------------------------
extern "C" void kernel_launch(void* const* d_in, const int* in_sizes, int n_in,
                              void* d_out, int out_size, void* d_ws, size_t ws_size,
                              hipStream_t stream) {
    const float* enc = (const float*)d_in[0];
    const float* dec = (const float*)d_in[1];
    const float* W1  = (const float*)d_in[2];
    const float* b1  = (const float*)d_in[3];
    const float* W2  = (const float*)d_in[4];
    const float* b2  = (const float*)d_in[5];
    float* out = (float*)d_out;

    // Workspace (d_ws), ~69.3 MB:
    char* ws = (char*)d_ws;
    float*  encp = (float*)ws;                                   // 640*640*4   (b1 folded)
    float*  decp = (float*)(ws + 1638400);                       // 320*640*4
    __bf16* W2t  = (__bf16*)(ws + 1638400 + 819200);             // 1024*640*2
    __bf16* Hbuf = (__bf16*)(ws + 1638400 + 819200 + 1310720);   // 51200*640*2

    proj_kernel<<<dim3(10, 15), 256, 0, stream>>>(enc, dec, W1, b1, encp, decp);
    w2t_kernel<<<dim3(32, 20), 256, 0, stream>>>(W2, W2t);
    hidden_kernel<<<16000, 256, 0, stream>>>(encp, decp, Hbuf);
    gemm_kernel<<<800, 512, 0, stream>>>(Hbuf, W2t, b2, out);
}